// Round 1
// baseline (525.230 us; speedup 1.0000x reference)
//
#include <hip/hip_runtime.h>
#include <hip/hip_bf16.h>

#define NEG_SLOPE 0.2f

__device__ __forceinline__ float lrelu(float x) { return x > 0.f ? x : NEG_SLOPE * x; }

// ---------- edge-index dtype detection (int32 vs int64) ----------
__global__ void detect_kernel(const int* __restrict__ ei, int* __restrict__ flag) {
    if (threadIdx.x == 0 && blockIdx.x == 0) {
        int z = 1;
        for (int i = 0; i < 64; ++i) if (ei[2 * i + 1] != 0) { z = 0; break; }
        *flag = z;  // 1 => buffer is int64 little-endian
    }
}

__device__ __forceinline__ int load_src(const int* ei, int E, int e, int is64) {
    return is64 ? ei[2 * (size_t)e] : ei[e];
}
__device__ __forceinline__ int load_dst(const int* ei, int E, int e, int is64) {
    return is64 ? ei[2 * (size_t)E + 2 * (size_t)e] : ei[(size_t)E + e];
}

// ---------- CSR build ----------
__global__ void deg_kernel(const int* __restrict__ ei, int E, int* __restrict__ cnt,
                           const int* __restrict__ flag) {
    int e = blockIdx.x * blockDim.x + threadIdx.x;
    if (e < E) {
        int d = load_dst(ei, E, e, *flag);
        atomicAdd(&cnt[d], 1);
    }
}

__global__ void scan_kernel(int* __restrict__ cnt, int* __restrict__ offs, int n) {
    __shared__ int sums[256];
    int t = threadIdx.x;
    int chunk = (n + 255) / 256;
    int lo = t * chunk;
    int hi = lo + chunk; if (hi > n) hi = n;
    int s = 0;
    for (int i = lo; i < hi; ++i) s += cnt[i] + 1;   // +1 self-loop
    sums[t] = s;
    __syncthreads();
    if (t == 0) {
        int acc = 0;
        for (int i = 0; i < 256; ++i) { int v = sums[i]; sums[i] = acc; acc += v; }
        offs[n] = acc;
    }
    __syncthreads();
    int acc = sums[t];
    for (int i = lo; i < hi; ++i) {
        int dv = cnt[i];
        offs[i] = acc;
        cnt[i]  = acc;   // becomes fill cursor
        acc += dv + 1;
    }
}

__global__ void fill_kernel(const int* __restrict__ ei, int E, int n,
                            int* __restrict__ cursor, int* __restrict__ csr,
                            const int* __restrict__ flag) {
    int e = blockIdx.x * blockDim.x + threadIdx.x;
    if (e < E + n) {
        int s, d;
        if (e < E) { int f = *flag; s = load_src(ei, E, e, f); d = load_dst(ei, E, e, f); }
        else       { s = d = e - E; }
        int pos = atomicAdd(&cursor[d], 1);
        csr[pos] = s;
    }
}

// ---------- layer-1 GEMM: h1[N,256] = x[N,128] @ W1[128,256] ----------
__global__ __launch_bounds__(256) void gemm1_kernel(const float* __restrict__ x,
                                                    const float* __restrict__ W1,
                                                    float* __restrict__ h1, int n) {
    __shared__ float xs[32][128];  // 16 KB, row-major; compute reads are uniform-address broadcasts
    int row0 = blockIdx.x * 32;
    int t = threadIdx.x;
    for (int i = t; i < 1024; i += 256) {      // 1024 float4 = 32 rows * 32 quads
        int r = i >> 5, kq = i & 31;
        float4 v = make_float4(0.f, 0.f, 0.f, 0.f);
        if (row0 + r < n) v = ((const float4*)x)[(size_t)(row0 + r) * 32 + kq];
        *(float4*)&xs[r][4 * kq] = v;
    }
    __syncthreads();
    float acc[32];
#pragma unroll
    for (int r = 0; r < 32; ++r) acc[r] = 0.f;
    for (int kq = 0; kq < 32; ++kq) {
        float wa = W1[(4 * kq + 0) * 256 + t];
        float wb = W1[(4 * kq + 1) * 256 + t];
        float wc = W1[(4 * kq + 2) * 256 + t];
        float wd = W1[(4 * kq + 3) * 256 + t];
#pragma unroll
        for (int r = 0; r < 32; ++r) {
            float4 xv = *(const float4*)&xs[r][4 * kq];
            acc[r] = fmaf(xv.x, wa, acc[r]);
            acc[r] = fmaf(xv.y, wb, acc[r]);
            acc[r] = fmaf(xv.z, wc, acc[r]);
            acc[r] = fmaf(xv.w, wd, acc[r]);
        }
    }
#pragma unroll
    for (int r = 0; r < 32; ++r)
        if (row0 + r < n) h1[(size_t)(row0 + r) * 256 + t] = acc[r];
}

// ---------- attention dot products: a_src1/a_dst1 [N,8] ----------
__global__ void att_kernel(const float* __restrict__ h1, const float* __restrict__ att_src1,
                           const float* __restrict__ att_dst1, float* __restrict__ asrc1,
                           float* __restrict__ adst1, int total) {
    int idx = blockIdx.x * blockDim.x + threadIdx.x;  // idx = n*8 + h
    if (idx >= total) return;
    int h = idx & 7;
    const float4* hv = (const float4*)(h1 + (size_t)(idx >> 3) * 256 + h * 32);
    const float4* av = (const float4*)(att_src1 + h * 32);
    const float4* bv = (const float4*)(att_dst1 + h * 32);
    float sa = 0.f, sb = 0.f;
#pragma unroll
    for (int q = 0; q < 8; ++q) {
        float4 xv = hv[q], a = av[q], b = bv[q];
        sa += xv.x * a.x + xv.y * a.y + xv.z * a.z + xv.w * a.w;
        sb += xv.x * b.x + xv.y * b.y + xv.z * b.z + xv.w * b.w;
    }
    asrc1[idx] = sa;
    adst1[idx] = sb;
}

// ---------- segment softmax stats (max + denom), 1 wave per dst node ----------
__global__ void stats_kernel(const int* __restrict__ offs, const int* __restrict__ csr,
                             const float* __restrict__ asrc1, const float* __restrict__ adst1,
                             float* __restrict__ m1, float* __restrict__ dn1) {
    int d = blockIdx.x;
    int lane = threadIdx.x;
    int off = offs[d], end = offs[d + 1];
    float4 adl = ((const float4*)(adst1 + (size_t)d * 8))[0];
    float4 adh = ((const float4*)(adst1 + (size_t)d * 8))[1];
    float ad[8] = {adl.x, adl.y, adl.z, adl.w, adh.x, adh.y, adh.z, adh.w};
    float mx[8];
#pragma unroll
    for (int h = 0; h < 8; ++h) mx[h] = -1e30f;
    for (int i = off + lane; i < end; i += 64) {
        int s = csr[i];
        float4 a0 = ((const float4*)(asrc1 + (size_t)s * 8))[0];
        float4 a1 = ((const float4*)(asrc1 + (size_t)s * 8))[1];
        float ev[8] = {a0.x, a0.y, a0.z, a0.w, a1.x, a1.y, a1.z, a1.w};
#pragma unroll
        for (int h = 0; h < 8; ++h) mx[h] = fmaxf(mx[h], lrelu(ev[h] + ad[h]));
    }
#pragma unroll
    for (int h = 0; h < 8; ++h)
        for (int o = 32; o > 0; o >>= 1) mx[h] = fmaxf(mx[h], __shfl_xor(mx[h], o));
    float sm[8];
#pragma unroll
    for (int h = 0; h < 8; ++h) sm[h] = 0.f;
    for (int i = off + lane; i < end; i += 64) {
        int s = csr[i];
        float4 a0 = ((const float4*)(asrc1 + (size_t)s * 8))[0];
        float4 a1 = ((const float4*)(asrc1 + (size_t)s * 8))[1];
        float ev[8] = {a0.x, a0.y, a0.z, a0.w, a1.x, a1.y, a1.z, a1.w};
#pragma unroll
        for (int h = 0; h < 8; ++h) sm[h] += __expf(lrelu(ev[h] + ad[h]) - mx[h]);
    }
#pragma unroll
    for (int h = 0; h < 8; ++h)
        for (int o = 32; o > 0; o >>= 1) sm[h] += __shfl_xor(sm[h], o);
    if (lane == 0) {
#pragma unroll
        for (int h = 0; h < 8; ++h) { m1[(size_t)d * 8 + h] = mx[h]; dn1[(size_t)d * 8 + h] = sm[h]; }
    }
}

// ---------- fused: aggregate + bias + ELU + @W2 + layer-2 att dots ----------
__global__ __launch_bounds__(256) void aggregate_kernel(
        const int* __restrict__ offs, const int* __restrict__ csr,
        const float* __restrict__ asrc1, const float* __restrict__ adst1,
        const float* __restrict__ m1, const float* __restrict__ dn1,
        const float* __restrict__ h1, const float* __restrict__ b1,
        const float* __restrict__ W2, const float* __restrict__ att_src2,
        const float* __restrict__ att_dst2,
        float* __restrict__ h2, float* __restrict__ asrc2, float* __restrict__ adst2) {
    int d = blockIdx.x;
    int t = threadIdx.x;
    int h = t >> 5;
    int off = offs[d], end = offs[d + 1];
    float adh = adst1[(size_t)d * 8 + h];
    float mh  = m1[(size_t)d * 8 + h];
    float inv = 1.0f / dn1[(size_t)d * 8 + h];
    float acc = 0.f;
    int i = off;
    for (; i + 4 <= end; i += 4) {
        int s0 = csr[i], s1 = csr[i + 1], s2 = csr[i + 2], s3 = csr[i + 3];
        float a0 = asrc1[(size_t)s0 * 8 + h], a1 = asrc1[(size_t)s1 * 8 + h];
        float a2 = asrc1[(size_t)s2 * 8 + h], a3 = asrc1[(size_t)s3 * 8 + h];
        float v0 = h1[(size_t)s0 * 256 + t], v1 = h1[(size_t)s1 * 256 + t];
        float v2 = h1[(size_t)s2 * 256 + t], v3 = h1[(size_t)s3 * 256 + t];
        acc = fmaf(__expf(lrelu(a0 + adh) - mh), v0, acc);
        acc = fmaf(__expf(lrelu(a1 + adh) - mh), v1, acc);
        acc = fmaf(__expf(lrelu(a2 + adh) - mh), v2, acc);
        acc = fmaf(__expf(lrelu(a3 + adh) - mh), v3, acc);
    }
    for (; i < end; ++i) {
        int s = csr[i];
        float a = asrc1[(size_t)s * 8 + h];
        float v = h1[(size_t)s * 256 + t];
        acc = fmaf(__expf(lrelu(a + adh) - mh), v, acc);
    }
    acc *= inv;
    float v = acc + b1[t];
    v = v > 0.f ? v : __expf(v) - 1.f;      // ELU
    // layer-2 transform: h2 = v_row @ W2  (256 -> 2), block reduce
    float p0 = v * W2[2 * t];
    float p1 = v * W2[2 * t + 1];
#pragma unroll
    for (int o = 32; o > 0; o >>= 1) { p0 += __shfl_down(p0, o); p1 += __shfl_down(p1, o); }
    __shared__ float red[8];
    int wid = t >> 6;
    if ((t & 63) == 0) { red[wid * 2] = p0; red[wid * 2 + 1] = p1; }
    __syncthreads();
    if (t == 0) {
        float h20 = red[0] + red[2] + red[4] + red[6];
        float h21 = red[1] + red[3] + red[5] + red[7];
        h2[(size_t)d * 2 + 0] = h20;
        h2[(size_t)d * 2 + 1] = h21;
        asrc2[d] = h20 * att_src2[0] + h21 * att_src2[1];
        adst2[d] = h20 * att_dst2[0] + h21 * att_dst2[1];
    }
}

// ---------- layer-2 softmax + aggregate + log_softmax, 1 wave per node ----------
__global__ void layer2_kernel(const int* __restrict__ offs, const int* __restrict__ csr,
                              const float* __restrict__ asrc2, const float* __restrict__ adst2,
                              const float* __restrict__ h2, const float* __restrict__ b2,
                              float* __restrict__ out) {
    int d = blockIdx.x;
    int lane = threadIdx.x;
    int off = offs[d], end = offs[d + 1];
    float ad = adst2[d];
    float mx = -1e30f;
    for (int i = off + lane; i < end; i += 64) {
        int s = csr[i];
        mx = fmaxf(mx, lrelu(asrc2[s] + ad));
    }
#pragma unroll
    for (int o = 32; o > 0; o >>= 1) mx = fmaxf(mx, __shfl_xor(mx, o));
    float se = 0.f, s0 = 0.f, s1 = 0.f;
    for (int i = off + lane; i < end; i += 64) {
        int s = csr[i];
        float e = __expf(lrelu(asrc2[s] + ad) - mx);
        se += e;
        s0 = fmaf(e, h2[(size_t)s * 2 + 0], s0);
        s1 = fmaf(e, h2[(size_t)s * 2 + 1], s1);
    }
#pragma unroll
    for (int o = 32; o > 0; o >>= 1) {
        se += __shfl_xor(se, o); s0 += __shfl_xor(s0, o); s1 += __shfl_xor(s1, o);
    }
    if (lane == 0) {
        float o0 = s0 / se + b2[0];
        float o1 = s1 / se + b2[1];
        float m2 = fmaxf(o0, o1);
        float lse = m2 + logf(__expf(o0 - m2) + __expf(o1 - m2));
        out[(size_t)d * 2 + 0] = o0 - lse;
        out[(size_t)d * 2 + 1] = o1 - lse;
    }
}

extern "C" void kernel_launch(void* const* d_in, const int* in_sizes, int n_in,
                              void* d_out, int out_size, void* d_ws, size_t ws_size,
                              hipStream_t stream) {
    const float* x        = (const float*)d_in[0];
    const int*   ei       = (const int*)d_in[1];
    const float* W1       = (const float*)d_in[2];
    const float* att_src1 = (const float*)d_in[3];
    const float* att_dst1 = (const float*)d_in[4];
    const float* b1       = (const float*)d_in[5];
    const float* W2       = (const float*)d_in[6];
    const float* att_src2 = (const float*)d_in[7];
    const float* att_dst2 = (const float*)d_in[8];
    const float* b2       = (const float*)d_in[9];
    float* out = (float*)d_out;

    int N = in_sizes[0] / 128;   // 50000
    int E = in_sizes[1] / 2;     // 800000

    // workspace layout (~62.3 MB)
    float* h1    = (float*)d_ws;                 // N*256
    float* asrc1 = h1 + (size_t)N * 256;         // N*8
    float* adst1 = asrc1 + (size_t)N * 8;        // N*8
    float* m1    = adst1 + (size_t)N * 8;        // N*8
    float* dn1   = m1 + (size_t)N * 8;           // N*8
    float* h2    = dn1 + (size_t)N * 8;          // N*2
    float* asrc2 = h2 + (size_t)N * 2;           // N
    float* adst2 = asrc2 + N;                    // N
    int*   offs   = (int*)(adst2 + N);           // N+1
    int*   cursor = offs + (N + 1);              // N
    int*   csr    = cursor + N;                  // E+N
    int*   flag   = csr + ((size_t)E + N);       // 1

    detect_kernel<<<1, 64, 0, stream>>>(ei, flag);
    hipMemsetAsync(cursor, 0, (size_t)N * sizeof(int), stream);
    deg_kernel<<<(E + 255) / 256, 256, 0, stream>>>(ei, E, cursor, flag);
    scan_kernel<<<1, 256, 0, stream>>>(cursor, offs, N);
    fill_kernel<<<(E + N + 255) / 256, 256, 0, stream>>>(ei, E, N, cursor, csr, flag);
    gemm1_kernel<<<(N + 31) / 32, 256, 0, stream>>>(x, W1, h1, N);
    att_kernel<<<(N * 8 + 255) / 256, 256, 0, stream>>>(h1, att_src1, att_dst1, asrc1, adst1, N * 8);
    stats_kernel<<<N, 64, 0, stream>>>(offs, csr, asrc1, adst1, m1, dn1);
    aggregate_kernel<<<N, 256, 0, stream>>>(offs, csr, asrc1, adst1, m1, dn1, h1, b1,
                                            W2, att_src2, att_dst2, h2, asrc2, adst2);
    layer2_kernel<<<N, 64, 0, stream>>>(offs, csr, asrc2, adst2, h2, b2, out);
}

// Round 2
// 343.096 us; speedup vs baseline: 1.5309x; 1.5309x over previous
//
#include <hip/hip_runtime.h>
#include <hip/hip_bf16.h>

#define NEG_SLOPE 0.2f

__device__ __forceinline__ float lrelu(float x) { return x > 0.f ? x : NEG_SLOPE * x; }

// ---------- edge-index dtype detection (int32 vs int64) ----------
__global__ void detect_kernel(const int* __restrict__ ei, int* __restrict__ flag) {
    if (threadIdx.x == 0 && blockIdx.x == 0) {
        int z = 1;
        for (int i = 0; i < 64; ++i) if (ei[2 * i + 1] != 0) { z = 0; break; }
        *flag = z;  // 1 => buffer is int64 little-endian
    }
}

__device__ __forceinline__ int load_src(const int* ei, int E, int e, int is64) {
    return is64 ? ei[2 * (size_t)e] : ei[e];
}
__device__ __forceinline__ int load_dst(const int* ei, int E, int e, int is64) {
    return is64 ? ei[2 * (size_t)E + 2 * (size_t)e] : ei[(size_t)E + e];
}

// ---------- CSR build ----------
__global__ void deg_kernel(const int* __restrict__ ei, int E, int* __restrict__ cnt,
                           const int* __restrict__ flag) {
    int e = blockIdx.x * blockDim.x + threadIdx.x;
    if (e < E) {
        int d = load_dst(ei, E, e, *flag);
        atomicAdd(&cnt[d], 1);
    }
}

// scanA: per-256-block sums of (cnt[i]+1)
__global__ void scanA_kernel(const int* __restrict__ cnt, int n, int* __restrict__ bsum) {
    int t = threadIdx.x;
    int i = blockIdx.x * 256 + t;
    int v = (i < n) ? cnt[i] + 1 : 0;
#pragma unroll
    for (int o = 32; o; o >>= 1) v += __shfl_down(v, o);
    __shared__ int ws[4];
    if ((t & 63) == 0) ws[t >> 6] = v;
    __syncthreads();
    if (t == 0) bsum[blockIdx.x] = ws[0] + ws[1] + ws[2] + ws[3];
}

// scanB: exclusive scan of block sums (single block), writes offs[n]=total
__global__ void scanB_kernel(int* __restrict__ bsum, int nb, int* __restrict__ offs, int n) {
    __shared__ int sd[256];
    int t = threadIdx.x;
    int chunk = (nb + 255) / 256;
    int lo = t * chunk;
    int hi = lo + chunk; if (hi > nb) hi = nb;
    int s = 0;
    for (int i = lo; i < hi; ++i) s += bsum[i];
    sd[t] = s;
    __syncthreads();
    for (int o = 1; o < 256; o <<= 1) {
        int x = (t >= o) ? sd[t - o] : 0;
        __syncthreads();
        sd[t] += x;
        __syncthreads();
    }
    int run = sd[t] - s;
    for (int i = lo; i < hi; ++i) { int v = bsum[i]; bsum[i] = run; run += v; }
    if (t == 0) offs[n] = sd[255];
}

// scanC: in-block exclusive scan + block base -> offs[i], cursor[i]
__global__ void scanC_kernel(int* __restrict__ cnt, int n, const int* __restrict__ bsum,
                             int* __restrict__ offs) {
    __shared__ int sd[256];
    int t = threadIdx.x;
    int i = blockIdx.x * 256 + t;
    int v = (i < n) ? cnt[i] + 1 : 0;
    sd[t] = v;
    __syncthreads();
    for (int o = 1; o < 256; o <<= 1) {
        int x = (t >= o) ? sd[t - o] : 0;
        __syncthreads();
        sd[t] += x;
        __syncthreads();
    }
    int excl = sd[t] - v + bsum[blockIdx.x];
    if (i < n) { offs[i] = excl; cnt[i] = excl; }
}

__global__ void fill_kernel(const int* __restrict__ ei, int E, int n,
                            int* __restrict__ cursor, int* __restrict__ csr,
                            const int* __restrict__ flag) {
    int e = blockIdx.x * blockDim.x + threadIdx.x;
    if (e < E + n) {
        int s, d;
        if (e < E) { int f = *flag; s = load_src(ei, E, e, f); d = load_dst(ei, E, e, f); }
        else       { s = d = e - E; }
        int pos = atomicAdd(&cursor[d], 1);
        csr[pos] = s;
    }
}

// ---------- layer-1 GEMM + fused attention dots ----------
// h1[N,256] = x[N,128] @ W1[128,256]  (stored bf16)
// asrc1/adst1[N,8] = per-head dots with att vectors (fp32, from fp32 accs)
__global__ __launch_bounds__(256) void gemm1_kernel(
        const float* __restrict__ x, const float* __restrict__ W1,
        const float* __restrict__ att_src1, const float* __restrict__ att_dst1,
        __hip_bfloat16* __restrict__ h1, float* __restrict__ asrc1,
        float* __restrict__ adst1, int n) {
    __shared__ float xs[32][128];  // broadcast reads in main loop (uniform address)
    int row0 = blockIdx.x * 32;
    int t = threadIdx.x;
    for (int i = t; i < 1024; i += 256) {
        int r = i >> 5, kq = i & 31;
        float4 v = make_float4(0.f, 0.f, 0.f, 0.f);
        if (row0 + r < n) v = ((const float4*)x)[(size_t)(row0 + r) * 32 + kq];
        *(float4*)&xs[r][4 * kq] = v;
    }
    __syncthreads();
    int c = t & 63, rg = t >> 6, r0 = rg * 8;
    float acc[8][4];
#pragma unroll
    for (int r = 0; r < 8; ++r)
#pragma unroll
        for (int j = 0; j < 4; ++j) acc[r][j] = 0.f;

    for (int kq = 0; kq < 32; ++kq) {
        float wv[4][4];
#pragma unroll
        for (int kk = 0; kk < 4; ++kk)
#pragma unroll
            for (int j = 0; j < 4; ++j)
                wv[kk][j] = W1[(size_t)(4 * kq + kk) * 256 + c + 64 * j];
#pragma unroll
        for (int r = 0; r < 8; ++r) {
            float4 xv = *(const float4*)&xs[r0 + r][4 * kq];
#pragma unroll
            for (int j = 0; j < 4; ++j) {
                acc[r][j] = fmaf(xv.x, wv[0][j], acc[r][j]);
                acc[r][j] = fmaf(xv.y, wv[1][j], acc[r][j]);
                acc[r][j] = fmaf(xv.z, wv[2][j], acc[r][j]);
                acc[r][j] = fmaf(xv.w, wv[3][j], acc[r][j]);
            }
        }
    }
    // epilogue: store bf16 h1 + fused per-head attention dots
    int ch = c & 31;
    int hbase = c >> 5;           // cols c+64j have head hbase+2j
    float aS[4], aD[4];
#pragma unroll
    for (int j = 0; j < 4; ++j) {
        int hh = hbase + 2 * j;
        aS[j] = att_src1[hh * 32 + ch];
        aD[j] = att_dst1[hh * 32 + ch];
    }
#pragma unroll
    for (int r = 0; r < 8; ++r) {
        int row = row0 + r0 + r;
        float sv[4], dv[4];
#pragma unroll
        for (int j = 0; j < 4; ++j) { sv[j] = acc[r][j] * aS[j]; dv[j] = acc[r][j] * aD[j]; }
#pragma unroll
        for (int o = 16; o; o >>= 1) {
#pragma unroll
            for (int j = 0; j < 4; ++j) {
                sv[j] += __shfl_xor(sv[j], o, 32);
                dv[j] += __shfl_xor(dv[j], o, 32);
            }
        }
        if (row < n) {
#pragma unroll
            for (int j = 0; j < 4; ++j)
                h1[(size_t)row * 256 + c + 64 * j] = __float2bfloat16(acc[r][j]);
            if (ch == 0) {
#pragma unroll
                for (int j = 0; j < 4; ++j) {
                    int hh = hbase + 2 * j;
                    asrc1[(size_t)row * 8 + hh] = sv[j];
                    adst1[(size_t)row * 8 + hh] = dv[j];
                }
            }
        }
    }
}

// ---------- segment softmax: max, denom, and normalized alpha per (edge,head) ----------
__global__ void stats_kernel(const int* __restrict__ offs, const int* __restrict__ csr,
                             const float* __restrict__ asrc1, const float* __restrict__ adst1,
                             float* __restrict__ alpha) {
    int d = blockIdx.x;
    int lane = threadIdx.x;
    int off = offs[d], end = offs[d + 1];
    float4 adl = ((const float4*)(adst1 + (size_t)d * 8))[0];
    float4 adh = ((const float4*)(adst1 + (size_t)d * 8))[1];
    float ad[8] = {adl.x, adl.y, adl.z, adl.w, adh.x, adh.y, adh.z, adh.w};
    float mx[8];
#pragma unroll
    for (int h = 0; h < 8; ++h) mx[h] = -1e30f;
    for (int i = off + lane; i < end; i += 64) {
        int s = csr[i];
        float4 a0 = ((const float4*)(asrc1 + (size_t)s * 8))[0];
        float4 a1 = ((const float4*)(asrc1 + (size_t)s * 8))[1];
        float ev[8] = {a0.x, a0.y, a0.z, a0.w, a1.x, a1.y, a1.z, a1.w};
#pragma unroll
        for (int h = 0; h < 8; ++h) mx[h] = fmaxf(mx[h], lrelu(ev[h] + ad[h]));
    }
#pragma unroll
    for (int h = 0; h < 8; ++h)
        for (int o = 32; o > 0; o >>= 1) mx[h] = fmaxf(mx[h], __shfl_xor(mx[h], o));
    float sm[8];
#pragma unroll
    for (int h = 0; h < 8; ++h) sm[h] = 0.f;
    for (int i = off + lane; i < end; i += 64) {
        int s = csr[i];
        float4 a0 = ((const float4*)(asrc1 + (size_t)s * 8))[0];
        float4 a1 = ((const float4*)(asrc1 + (size_t)s * 8))[1];
        float ev[8] = {a0.x, a0.y, a0.z, a0.w, a1.x, a1.y, a1.z, a1.w};
#pragma unroll
        for (int h = 0; h < 8; ++h) sm[h] += __expf(lrelu(ev[h] + ad[h]) - mx[h]);
    }
#pragma unroll
    for (int h = 0; h < 8; ++h)
        for (int o = 32; o > 0; o >>= 1) sm[h] += __shfl_xor(sm[h], o);
    float inv[8];
#pragma unroll
    for (int h = 0; h < 8; ++h) inv[h] = 1.0f / sm[h];
    // third pass: write normalized alpha (coalesced float4 x2 per edge)
    for (int i = off + lane; i < end; i += 64) {
        int s = csr[i];
        float4 a0 = ((const float4*)(asrc1 + (size_t)s * 8))[0];
        float4 a1 = ((const float4*)(asrc1 + (size_t)s * 8))[1];
        float ev[8] = {a0.x, a0.y, a0.z, a0.w, a1.x, a1.y, a1.z, a1.w};
        float w[8];
#pragma unroll
        for (int h = 0; h < 8; ++h) w[h] = __expf(lrelu(ev[h] + ad[h]) - mx[h]) * inv[h];
        ((float4*)(alpha + (size_t)i * 8))[0] = make_float4(w[0], w[1], w[2], w[3]);
        ((float4*)(alpha + (size_t)i * 8))[1] = make_float4(w[4], w[5], w[6], w[7]);
    }
}

// ---------- fused: aggregate (bf16 gather) + bias + ELU + @W2 + layer-2 att dots ----------
__global__ __launch_bounds__(256) void aggregate_kernel(
        const int* __restrict__ offs, const int* __restrict__ csr,
        const float* __restrict__ alpha, const __hip_bfloat16* __restrict__ h1,
        const float* __restrict__ b1, const float* __restrict__ W2,
        const float* __restrict__ att_src2, const float* __restrict__ att_dst2,
        float* __restrict__ h2, float* __restrict__ asrc2, float* __restrict__ adst2) {
    int d = blockIdx.x;
    int t = threadIdx.x;
    int h = t >> 5;
    int off = offs[d], end = offs[d + 1];
    float acc = 0.f;
    int i = off;
    for (; i + 4 <= end; i += 4) {
        int s0 = csr[i], s1 = csr[i + 1], s2 = csr[i + 2], s3 = csr[i + 3];
        float al0 = alpha[(size_t)(i + 0) * 8 + h];
        float al1 = alpha[(size_t)(i + 1) * 8 + h];
        float al2 = alpha[(size_t)(i + 2) * 8 + h];
        float al3 = alpha[(size_t)(i + 3) * 8 + h];
        float v0 = __bfloat162float(h1[(size_t)s0 * 256 + t]);
        float v1 = __bfloat162float(h1[(size_t)s1 * 256 + t]);
        float v2 = __bfloat162float(h1[(size_t)s2 * 256 + t]);
        float v3 = __bfloat162float(h1[(size_t)s3 * 256 + t]);
        acc = fmaf(al0, v0, acc);
        acc = fmaf(al1, v1, acc);
        acc = fmaf(al2, v2, acc);
        acc = fmaf(al3, v3, acc);
    }
    for (; i < end; ++i) {
        int s = csr[i];
        float al = alpha[(size_t)i * 8 + h];
        float v = __bfloat162float(h1[(size_t)s * 256 + t]);
        acc = fmaf(al, v, acc);
    }
    float v = acc + b1[t];
    v = v > 0.f ? v : __expf(v) - 1.f;      // ELU
    float p0 = v * W2[2 * t];
    float p1 = v * W2[2 * t + 1];
#pragma unroll
    for (int o = 32; o > 0; o >>= 1) { p0 += __shfl_down(p0, o); p1 += __shfl_down(p1, o); }
    __shared__ float red[8];
    int wid = t >> 6;
    if ((t & 63) == 0) { red[wid * 2] = p0; red[wid * 2 + 1] = p1; }
    __syncthreads();
    if (t == 0) {
        float h20 = red[0] + red[2] + red[4] + red[6];
        float h21 = red[1] + red[3] + red[5] + red[7];
        h2[(size_t)d * 2 + 0] = h20;
        h2[(size_t)d * 2 + 1] = h21;
        asrc2[d] = h20 * att_src2[0] + h21 * att_src2[1];
        adst2[d] = h20 * att_dst2[0] + h21 * att_dst2[1];
    }
}

// ---------- layer-2: single-pass online softmax + aggregate + log_softmax ----------
__global__ void layer2_kernel(const int* __restrict__ offs, const int* __restrict__ csr,
                              const float* __restrict__ asrc2, const float* __restrict__ adst2,
                              const float* __restrict__ h2, const float* __restrict__ b2,
                              float* __restrict__ out) {
    int d = blockIdx.x;
    int lane = threadIdx.x;
    int off = offs[d], end = offs[d + 1];
    float ad = adst2[d];
    float m = -1e30f, se = 0.f, s0 = 0.f, s1 = 0.f;
    for (int i = off + lane; i < end; i += 64) {
        int s = csr[i];
        float e = lrelu(asrc2[s] + ad);
        if (e > m) {
            float sc = __expf(m - e);
            se *= sc; s0 *= sc; s1 *= sc; m = e;
        }
        float p = __expf(e - m);
        se += p;
        s0 = fmaf(p, h2[(size_t)s * 2 + 0], s0);
        s1 = fmaf(p, h2[(size_t)s * 2 + 1], s1);
    }
#pragma unroll
    for (int o = 32; o > 0; o >>= 1) {
        float mo = __shfl_xor(m, o);
        float seo = __shfl_xor(se, o);
        float s0o = __shfl_xor(s0, o);
        float s1o = __shfl_xor(s1, o);
        float mn = fmaxf(m, mo);
        float c1 = __expf(m - mn), c2 = __expf(mo - mn);
        se = se * c1 + seo * c2;
        s0 = s0 * c1 + s0o * c2;
        s1 = s1 * c1 + s1o * c2;
        m = mn;
    }
    if (lane == 0) {
        float o0 = s0 / se + b2[0];
        float o1 = s1 / se + b2[1];
        float m2 = fmaxf(o0, o1);
        float lse = m2 + logf(__expf(o0 - m2) + __expf(o1 - m2));
        out[(size_t)d * 2 + 0] = o0 - lse;
        out[(size_t)d * 2 + 1] = o1 - lse;
    }
}

extern "C" void kernel_launch(void* const* d_in, const int* in_sizes, int n_in,
                              void* d_out, int out_size, void* d_ws, size_t ws_size,
                              hipStream_t stream) {
    const float* x        = (const float*)d_in[0];
    const int*   ei       = (const int*)d_in[1];
    const float* W1       = (const float*)d_in[2];
    const float* att_src1 = (const float*)d_in[3];
    const float* att_dst1 = (const float*)d_in[4];
    const float* b1       = (const float*)d_in[5];
    const float* W2       = (const float*)d_in[6];
    const float* att_src2 = (const float*)d_in[7];
    const float* att_dst2 = (const float*)d_in[8];
    const float* b2       = (const float*)d_in[9];
    float* out = (float*)d_out;

    int N = in_sizes[0] / 128;   // 50000
    int E = in_sizes[1] / 2;     // 800000
    int nb = (N + 255) / 256;

    // workspace layout (~60.7 MB)
    __hip_bfloat16* h1 = (__hip_bfloat16*)d_ws;                 // N*256 bf16
    float* asrc1 = (float*)((char*)d_ws + (size_t)N * 512);     // N*8
    float* adst1 = asrc1 + (size_t)N * 8;                       // N*8
    float* alpha = adst1 + (size_t)N * 8;                       // (E+N)*8
    float* h2    = alpha + (size_t)(E + N) * 8;                 // N*2
    float* asrc2 = h2 + (size_t)N * 2;                          // N
    float* adst2 = asrc2 + N;                                   // N
    int*   offs   = (int*)(adst2 + N);                          // N+1
    int*   cursor = offs + (N + 1);                             // N
    int*   bsum   = cursor + N;                                 // 4096
    int*   csr    = bsum + 4096;                                // E+N
    int*   flag   = csr + ((size_t)E + N);                      // 1

    detect_kernel<<<1, 64, 0, stream>>>(ei, flag);
    hipMemsetAsync(cursor, 0, (size_t)N * sizeof(int), stream);
    deg_kernel<<<(E + 255) / 256, 256, 0, stream>>>(ei, E, cursor, flag);
    scanA_kernel<<<nb, 256, 0, stream>>>(cursor, N, bsum);
    scanB_kernel<<<1, 256, 0, stream>>>(bsum, nb, offs, N);
    scanC_kernel<<<nb, 256, 0, stream>>>(cursor, N, bsum, offs);
    fill_kernel<<<(E + N + 255) / 256, 256, 0, stream>>>(ei, E, N, cursor, csr, flag);
    gemm1_kernel<<<(N + 31) / 32, 256, 0, stream>>>(x, W1, att_src1, att_dst1, h1, asrc1, adst1, N);
    stats_kernel<<<N, 64, 0, stream>>>(offs, csr, asrc1, adst1, alpha);
    aggregate_kernel<<<N, 256, 0, stream>>>(offs, csr, alpha, h1, b1, W2, att_src2, att_dst2,
                                            h2, asrc2, adst2);
    layer2_kernel<<<N, 64, 0, stream>>>(offs, csr, asrc2, adst2, h2, b2, out);
}

// Round 3
// 271.695 us; speedup vs baseline: 1.9332x; 1.2628x over previous
//
#include <hip/hip_runtime.h>
#include <hip/hip_bf16.h>

#define NEG_SLOPE 0.2f

__device__ __forceinline__ float lrelu(float x) { return x > 0.f ? x : NEG_SLOPE * x; }
__device__ __forceinline__ float bf2f(unsigned short u) {
    return __uint_as_float(((unsigned int)u) << 16);
}

// ---------- init: zero cursor + edge-index dtype detection ----------
__global__ void init_kernel(const int* __restrict__ ei, int* __restrict__ flag,
                            int* __restrict__ cursor, int n) {
    int i = blockIdx.x * 256 + threadIdx.x;
    if (i < n) cursor[i] = 0;
    if (i == 0) {
        int z = 1;
        for (int k = 0; k < 64; ++k) if (ei[2 * k + 1] != 0) { z = 0; break; }
        *flag = z;  // 1 => buffer is int64 little-endian
    }
}

__device__ __forceinline__ int load_src(const int* ei, int E, int e, int is64) {
    return is64 ? ei[2 * (size_t)e] : ei[e];
}
__device__ __forceinline__ int load_dst(const int* ei, int E, int e, int is64) {
    return is64 ? ei[2 * (size_t)E + 2 * (size_t)e] : ei[(size_t)E + e];
}

// ---------- CSR build ----------
__global__ void deg_kernel(const int* __restrict__ ei, int E, int* __restrict__ cnt,
                           const int* __restrict__ flag) {
    int e = blockIdx.x * blockDim.x + threadIdx.x;
    if (e < E) {
        int d = load_dst(ei, E, e, *flag);
        atomicAdd(&cnt[d], 1);
    }
}

__global__ void scanA_kernel(const int* __restrict__ cnt, int n, int* __restrict__ bsum) {
    int t = threadIdx.x;
    int i = blockIdx.x * 256 + t;
    int v = (i < n) ? cnt[i] + 1 : 0;
#pragma unroll
    for (int o = 32; o; o >>= 1) v += __shfl_down(v, o);
    __shared__ int ws[4];
    if ((t & 63) == 0) ws[t >> 6] = v;
    __syncthreads();
    if (t == 0) bsum[blockIdx.x] = ws[0] + ws[1] + ws[2] + ws[3];
}

__global__ void scanB_kernel(int* __restrict__ bsum, int nb, int* __restrict__ offs, int n) {
    __shared__ int sd[256];
    int t = threadIdx.x;
    int chunk = (nb + 255) / 256;
    int lo = t * chunk;
    int hi = lo + chunk; if (hi > nb) hi = nb;
    int s = 0;
    for (int i = lo; i < hi; ++i) s += bsum[i];
    sd[t] = s;
    __syncthreads();
    for (int o = 1; o < 256; o <<= 1) {
        int x = (t >= o) ? sd[t - o] : 0;
        __syncthreads();
        sd[t] += x;
        __syncthreads();
    }
    int run = sd[t] - s;
    for (int i = lo; i < hi; ++i) { int v = bsum[i]; bsum[i] = run; run += v; }
    if (t == 0) offs[n] = sd[255];
}

__global__ void scanC_kernel(int* __restrict__ cnt, int n, const int* __restrict__ bsum,
                             int* __restrict__ offs) {
    __shared__ int sd[256];
    int t = threadIdx.x;
    int i = blockIdx.x * 256 + t;
    int v = (i < n) ? cnt[i] + 1 : 0;
    sd[t] = v;
    __syncthreads();
    for (int o = 1; o < 256; o <<= 1) {
        int x = (t >= o) ? sd[t - o] : 0;
        __syncthreads();
        sd[t] += x;
        __syncthreads();
    }
    int excl = sd[t] - v + bsum[blockIdx.x];
    if (i < n) { offs[i] = excl; cnt[i] = excl; }
}

__global__ void fill_kernel(const int* __restrict__ ei, int E, int n,
                            int* __restrict__ cursor, int* __restrict__ csr,
                            const int* __restrict__ flag) {
    int e = blockIdx.x * blockDim.x + threadIdx.x;
    if (e < E + n) {
        int s, d;
        if (e < E) { int f = *flag; s = load_src(ei, E, e, f); d = load_dst(ei, E, e, f); }
        else       { s = d = e - E; }
        int pos = atomicAdd(&cursor[d], 1);
        csr[pos] = s;
    }
}

// ---------- layer-1 GEMM + fused attention dots ----------
__global__ __launch_bounds__(256) void gemm1_kernel(
        const float* __restrict__ x, const float* __restrict__ W1,
        const float* __restrict__ att_src1, const float* __restrict__ att_dst1,
        __hip_bfloat16* __restrict__ h1, float* __restrict__ asrc1,
        float* __restrict__ adst1, int n) {
    __shared__ float xs[32][128];
    int row0 = blockIdx.x * 32;
    int t = threadIdx.x;
    for (int i = t; i < 1024; i += 256) {
        int r = i >> 5, kq = i & 31;
        float4 v = make_float4(0.f, 0.f, 0.f, 0.f);
        if (row0 + r < n) v = ((const float4*)x)[(size_t)(row0 + r) * 32 + kq];
        *(float4*)&xs[r][4 * kq] = v;
    }
    __syncthreads();
    int c = t & 63, rg = t >> 6, r0 = rg * 8;
    float acc[8][4];
#pragma unroll
    for (int r = 0; r < 8; ++r)
#pragma unroll
        for (int j = 0; j < 4; ++j) acc[r][j] = 0.f;

    for (int kq = 0; kq < 32; ++kq) {
        float wv[4][4];
#pragma unroll
        for (int kk = 0; kk < 4; ++kk)
#pragma unroll
            for (int j = 0; j < 4; ++j)
                wv[kk][j] = W1[(size_t)(4 * kq + kk) * 256 + c + 64 * j];
#pragma unroll
        for (int r = 0; r < 8; ++r) {
            float4 xv = *(const float4*)&xs[r0 + r][4 * kq];
#pragma unroll
            for (int j = 0; j < 4; ++j) {
                acc[r][j] = fmaf(xv.x, wv[0][j], acc[r][j]);
                acc[r][j] = fmaf(xv.y, wv[1][j], acc[r][j]);
                acc[r][j] = fmaf(xv.z, wv[2][j], acc[r][j]);
                acc[r][j] = fmaf(xv.w, wv[3][j], acc[r][j]);
            }
        }
    }
    int ch = c & 31;
    int hbase = c >> 5;
    float aS[4], aD[4];
#pragma unroll
    for (int j = 0; j < 4; ++j) {
        int hh = hbase + 2 * j;
        aS[j] = att_src1[hh * 32 + ch];
        aD[j] = att_dst1[hh * 32 + ch];
    }
#pragma unroll
    for (int r = 0; r < 8; ++r) {
        int row = row0 + r0 + r;
        float sv[4], dv[4];
#pragma unroll
        for (int j = 0; j < 4; ++j) { sv[j] = acc[r][j] * aS[j]; dv[j] = acc[r][j] * aD[j]; }
#pragma unroll
        for (int o = 16; o; o >>= 1) {
#pragma unroll
            for (int j = 0; j < 4; ++j) {
                sv[j] += __shfl_xor(sv[j], o, 32);
                dv[j] += __shfl_xor(dv[j], o, 32);
            }
        }
        if (row < n) {
#pragma unroll
            for (int j = 0; j < 4; ++j)
                h1[(size_t)row * 256 + c + 64 * j] = __float2bfloat16(acc[r][j]);
            if (ch == 0) {
#pragma unroll
                for (int j = 0; j < 4; ++j) {
                    int hh = hbase + 2 * j;
                    asrc1[(size_t)row * 8 + hh] = sv[j];
                    adst1[(size_t)row * 8 + hh] = dv[j];
                }
            }
        }
    }
}

// ---------- stats: single pass, unnormalized exp -> alpha, per-head denom ----------
// 1 wave/node; lane = (edge_group<<3) | head
__global__ __launch_bounds__(64) void stats_kernel(
        const int* __restrict__ offs, const int* __restrict__ csr,
        const float* __restrict__ asrc1, const float* __restrict__ adst1,
        float* __restrict__ alpha, float* __restrict__ dn1) {
    int d = blockIdx.x;
    int lane = threadIdx.x;
    int h = lane & 7;
    int eg = lane >> 3;
    int off = offs[d], end = offs[d + 1];
    float ad = adst1[(size_t)d * 8 + h];
    float acc = 0.f;
    for (int i = off + eg; i < end; i += 8) {
        int s = csr[i];
        float a = asrc1[(size_t)s * 8 + h];
        float w = __expf(lrelu(a + ad));   // no-max: logits are O(1), safe in fp32
        alpha[(size_t)i * 8 + h] = w;
        acc += w;
    }
    acc += __shfl_xor(acc, 8);
    acc += __shfl_xor(acc, 16);
    acc += __shfl_xor(acc, 32);
    if (lane < 8) dn1[(size_t)d * 8 + lane] = acc;
}

// ---------- fused aggregate: 1 wave/node, 4 channels/lane ----------
__global__ __launch_bounds__(64) void aggregate_kernel(
        const int* __restrict__ offs, const int* __restrict__ csr,
        const float* __restrict__ alpha, const __hip_bfloat16* __restrict__ h1,
        const float* __restrict__ dn1, const float* __restrict__ b1,
        const float* __restrict__ W2, const float* __restrict__ att_src2,
        const float* __restrict__ att_dst2, float4* __restrict__ rec) {
    int d = blockIdx.x;
    int t = threadIdx.x;          // lane: channels 4t..4t+3
    int h = t >> 3;               // head of these channels
    int off = offs[d], end = offs[d + 1];
    float a0 = 0.f, a1 = 0.f, a2 = 0.f, a3 = 0.f;
    const unsigned short* h1u = (const unsigned short*)h1;
    int i = off;
    for (; i + 4 <= end; i += 4) {
        int s0 = csr[i], s1 = csr[i + 1], s2 = csr[i + 2], s3 = csr[i + 3];
        float al0 = alpha[(size_t)(i + 0) * 8 + h];
        float al1 = alpha[(size_t)(i + 1) * 8 + h];
        float al2 = alpha[(size_t)(i + 2) * 8 + h];
        float al3 = alpha[(size_t)(i + 3) * 8 + h];
        ushort4 v0 = *(const ushort4*)(h1u + (size_t)s0 * 256 + 4 * t);
        ushort4 v1 = *(const ushort4*)(h1u + (size_t)s1 * 256 + 4 * t);
        ushort4 v2 = *(const ushort4*)(h1u + (size_t)s2 * 256 + 4 * t);
        ushort4 v3 = *(const ushort4*)(h1u + (size_t)s3 * 256 + 4 * t);
        a0 = fmaf(al0, bf2f(v0.x), a0); a1 = fmaf(al0, bf2f(v0.y), a1);
        a2 = fmaf(al0, bf2f(v0.z), a2); a3 = fmaf(al0, bf2f(v0.w), a3);
        a0 = fmaf(al1, bf2f(v1.x), a0); a1 = fmaf(al1, bf2f(v1.y), a1);
        a2 = fmaf(al1, bf2f(v1.z), a2); a3 = fmaf(al1, bf2f(v1.w), a3);
        a0 = fmaf(al2, bf2f(v2.x), a0); a1 = fmaf(al2, bf2f(v2.y), a1);
        a2 = fmaf(al2, bf2f(v2.z), a2); a3 = fmaf(al2, bf2f(v2.w), a3);
        a0 = fmaf(al3, bf2f(v3.x), a0); a1 = fmaf(al3, bf2f(v3.y), a1);
        a2 = fmaf(al3, bf2f(v3.z), a2); a3 = fmaf(al3, bf2f(v3.w), a3);
    }
    for (; i < end; ++i) {
        int s = csr[i];
        float al = alpha[(size_t)i * 8 + h];
        ushort4 v = *(const ushort4*)(h1u + (size_t)s * 256 + 4 * t);
        a0 = fmaf(al, bf2f(v.x), a0); a1 = fmaf(al, bf2f(v.y), a1);
        a2 = fmaf(al, bf2f(v.z), a2); a3 = fmaf(al, bf2f(v.w), a3);
    }
    float inv = 1.0f / dn1[(size_t)d * 8 + h];
    float4 bv = *(const float4*)(b1 + 4 * t);
    float v0 = fmaf(a0, inv, bv.x);
    float v1 = fmaf(a1, inv, bv.y);
    float v2 = fmaf(a2, inv, bv.z);
    float v3 = fmaf(a3, inv, bv.w);
    v0 = v0 > 0.f ? v0 : __expf(v0) - 1.f;
    v1 = v1 > 0.f ? v1 : __expf(v1) - 1.f;
    v2 = v2 > 0.f ? v2 : __expf(v2) - 1.f;
    v3 = v3 > 0.f ? v3 : __expf(v3) - 1.f;
    float4 w01 = *(const float4*)(W2 + 8 * t);
    float4 w23 = *(const float4*)(W2 + 8 * t + 4);
    float p0 = v0 * w01.x + v1 * w01.z + v2 * w23.x + v3 * w23.z;
    float p1 = v0 * w01.y + v1 * w01.w + v2 * w23.y + v3 * w23.w;
#pragma unroll
    for (int o = 32; o; o >>= 1) { p0 += __shfl_down(p0, o); p1 += __shfl_down(p1, o); }
    if (t == 0) {
        float s2a = att_src2[0], s2b = att_src2[1];
        float d2a = att_dst2[0], d2b = att_dst2[1];
        rec[d] = make_float4(p0, p1, p0 * s2a + p1 * s2b, p0 * d2a + p1 * d2b);
    }
}

// ---------- layer-2: one float4 record gather per edge, no-max softmax ----------
__global__ __launch_bounds__(64) void layer2_kernel(
        const int* __restrict__ offs, const int* __restrict__ csr,
        const float4* __restrict__ rec, const float* __restrict__ b2,
        float* __restrict__ out) {
    int d = blockIdx.x;
    int lane = threadIdx.x;
    int off = offs[d], end = offs[d + 1];
    float ad = rec[d].w;
    float se = 0.f, s0 = 0.f, s1 = 0.f;
    for (int i = off + lane; i < end; i += 64) {
        int s = csr[i];
        float4 r = rec[s];
        float e = __expf(lrelu(r.z + ad));   // no-max: logits are O(0.1), safe
        se += e;
        s0 = fmaf(e, r.x, s0);
        s1 = fmaf(e, r.y, s1);
    }
#pragma unroll
    for (int o = 32; o; o >>= 1) {
        se += __shfl_xor(se, o); s0 += __shfl_xor(s0, o); s1 += __shfl_xor(s1, o);
    }
    if (lane == 0) {
        float o0 = s0 / se + b2[0];
        float o1 = s1 / se + b2[1];
        float m2 = fmaxf(o0, o1);
        float lse = m2 + logf(__expf(o0 - m2) + __expf(o1 - m2));
        out[(size_t)d * 2 + 0] = o0 - lse;
        out[(size_t)d * 2 + 1] = o1 - lse;
    }
}

extern "C" void kernel_launch(void* const* d_in, const int* in_sizes, int n_in,
                              void* d_out, int out_size, void* d_ws, size_t ws_size,
                              hipStream_t stream) {
    const float* x        = (const float*)d_in[0];
    const int*   ei       = (const int*)d_in[1];
    const float* W1       = (const float*)d_in[2];
    const float* att_src1 = (const float*)d_in[3];
    const float* att_dst1 = (const float*)d_in[4];
    const float* b1       = (const float*)d_in[5];
    const float* W2       = (const float*)d_in[6];
    const float* att_src2 = (const float*)d_in[7];
    const float* att_dst2 = (const float*)d_in[8];
    const float* b2       = (const float*)d_in[9];
    float* out = (float*)d_out;

    int N = in_sizes[0] / 128;   // 50000
    int E = in_sizes[1] / 2;     // 800000
    int nb = (N + 255) / 256;

    // workspace layout (~62 MB)
    __hip_bfloat16* h1 = (__hip_bfloat16*)d_ws;                 // N*256 bf16
    float* asrc1 = (float*)((char*)d_ws + (size_t)N * 512);     // N*8
    float* adst1 = asrc1 + (size_t)N * 8;                       // N*8
    float* alpha = adst1 + (size_t)N * 8;                       // (E+N)*8
    float* dn1   = alpha + (size_t)(E + N) * 8;                 // N*8
    float4* rec  = (float4*)(dn1 + (size_t)N * 8);              // N float4
    int*   offs   = (int*)(rec + N);                            // N+1
    int*   cursor = offs + (N + 1);                             // N
    int*   bsum   = cursor + N;                                 // 4096
    int*   csr    = bsum + 4096;                                // E+N
    int*   flag   = csr + ((size_t)E + N);                      // 1

    init_kernel<<<nb, 256, 0, stream>>>(ei, flag, cursor, N);
    deg_kernel<<<(E + 255) / 256, 256, 0, stream>>>(ei, E, cursor, flag);
    scanA_kernel<<<nb, 256, 0, stream>>>(cursor, N, bsum);
    scanB_kernel<<<1, 256, 0, stream>>>(bsum, nb, offs, N);
    scanC_kernel<<<nb, 256, 0, stream>>>(cursor, N, bsum, offs);
    fill_kernel<<<(E + N + 255) / 256, 256, 0, stream>>>(ei, E, N, cursor, csr, flag);
    gemm1_kernel<<<(N + 31) / 32, 256, 0, stream>>>(x, W1, att_src1, att_dst1, h1, asrc1, adst1, N);
    stats_kernel<<<N, 64, 0, stream>>>(offs, csr, asrc1, adst1, alpha, dn1);
    aggregate_kernel<<<N, 64, 0, stream>>>(offs, csr, alpha, h1, dn1, b1, W2,
                                           att_src2, att_dst2, rec);
    layer2_kernel<<<N, 64, 0, stream>>>(offs, csr, rec, b2, out);
}

// Round 4
// 257.531 us; speedup vs baseline: 2.0395x; 1.0550x over previous
//
#include <hip/hip_runtime.h>
#include <hip/hip_bf16.h>

#define NEG_SLOPE 0.2f

typedef float f32x4 __attribute__((ext_vector_type(4)));
typedef short s16x4 __attribute__((ext_vector_type(4)));
typedef short bf16x8 __attribute__((ext_vector_type(8)));

__device__ __forceinline__ float lrelu(float x) { return x > 0.f ? x : NEG_SLOPE * x; }
__device__ __forceinline__ float bf2f(unsigned short u) {
    return __uint_as_float(((unsigned int)u) << 16);
}
__device__ __forceinline__ unsigned short f2bf(float f) {   // RNE
    unsigned int u = __float_as_uint(f);
    return (unsigned short)((u + 0x7FFF + ((u >> 16) & 1)) >> 16);
}

// ---------- init: zero cursor + edge-index dtype detection ----------
__global__ void init_kernel(const int* __restrict__ ei, int* __restrict__ flag,
                            int* __restrict__ cursor, int n) {
    int i = blockIdx.x * 256 + threadIdx.x;
    if (i < n) cursor[i] = 0;
    if (i == 0) {
        int z = 1;
        for (int k = 0; k < 64; ++k) if (ei[2 * k + 1] != 0) { z = 0; break; }
        *flag = z;  // 1 => buffer is int64 little-endian
    }
}

__device__ __forceinline__ int load_src(const int* ei, int E, int e, int is64) {
    return is64 ? ei[2 * (size_t)e] : ei[e];
}
__device__ __forceinline__ int load_dst(const int* ei, int E, int e, int is64) {
    return is64 ? ei[2 * (size_t)E + 2 * (size_t)e] : ei[(size_t)E + e];
}

// ---------- CSR build ----------
__global__ void deg_kernel(const int* __restrict__ ei, int E, int* __restrict__ cnt,
                           const int* __restrict__ flag) {
    int e = blockIdx.x * blockDim.x + threadIdx.x;
    if (e < E) {
        int d = load_dst(ei, E, e, *flag);
        atomicAdd(&cnt[d], 1);
    }
}

__global__ void scanA_kernel(const int* __restrict__ cnt, int n, int* __restrict__ bsum) {
    int t = threadIdx.x;
    int i = blockIdx.x * 256 + t;
    int v = (i < n) ? cnt[i] + 1 : 0;
#pragma unroll
    for (int o = 32; o; o >>= 1) v += __shfl_down(v, o);
    __shared__ int ws[4];
    if ((t & 63) == 0) ws[t >> 6] = v;
    __syncthreads();
    if (t == 0) bsum[blockIdx.x] = ws[0] + ws[1] + ws[2] + ws[3];
}

__global__ void scanB_kernel(int* __restrict__ bsum, int nb, int* __restrict__ offs, int n) {
    __shared__ int sd[256];
    int t = threadIdx.x;
    int chunk = (nb + 255) / 256;
    int lo = t * chunk;
    int hi = lo + chunk; if (hi > nb) hi = nb;
    int s = 0;
    for (int i = lo; i < hi; ++i) s += bsum[i];
    sd[t] = s;
    __syncthreads();
    for (int o = 1; o < 256; o <<= 1) {
        int x = (t >= o) ? sd[t - o] : 0;
        __syncthreads();
        sd[t] += x;
        __syncthreads();
    }
    int run = sd[t] - s;
    for (int i = lo; i < hi; ++i) { int v = bsum[i]; bsum[i] = run; run += v; }
    if (t == 0) offs[n] = sd[255];
}

__global__ void scanC_kernel(int* __restrict__ cnt, int n, const int* __restrict__ bsum,
                             int* __restrict__ offs) {
    __shared__ int sd[256];
    int t = threadIdx.x;
    int i = blockIdx.x * 256 + t;
    int v = (i < n) ? cnt[i] + 1 : 0;
    sd[t] = v;
    __syncthreads();
    for (int o = 1; o < 256; o <<= 1) {
        int x = (t >= o) ? sd[t - o] : 0;
        __syncthreads();
        sd[t] += x;
        __syncthreads();
    }
    int excl = sd[t] - v + bsum[blockIdx.x];
    if (i < n) { offs[i] = excl; cnt[i] = excl; }
}

__global__ void fill_kernel(const int* __restrict__ ei, int E, int n,
                            int* __restrict__ cursor, int* __restrict__ csr,
                            const int* __restrict__ flag) {
    int e = blockIdx.x * blockDim.x + threadIdx.x;
    if (e < E + n) {
        int s, d;
        if (e < E) { int f = *flag; s = load_src(ei, E, e, f); d = load_dst(ei, E, e, f); }
        else       { s = d = e - E; }
        int pos = atomicAdd(&cursor[d], 1);
        csr[pos] = s;
    }
}

// ---------- prepass: W1T bf16 [272][128] = W1^T (256 rows) ++ P_src|P_dst (16 rows) ----------
// P[k][j] (j<8): sum_c W1[k][32j+c]*att_src1[j][c];  j in 8..15: att_dst1[j-8]
__global__ __launch_bounds__(256) void w1prep_kernel(
        const float* __restrict__ W1, const float* __restrict__ att_src1,
        const float* __restrict__ att_dst1, unsigned short* __restrict__ w1t) {
    int t = threadIdx.x;
    if (blockIdx.x < 128) {
        int v = blockIdx.x * 256 + t;       // 0..32767
        int col = v & 255, k = v >> 8;
        w1t[(size_t)col * 128 + k] = f2bf(W1[(size_t)k * 256 + col]);
    } else {
#pragma unroll
        for (int i = 0; i < 8; ++i) {
            int v = t + 256 * i;            // 0..2047
            int j = v & 15, k = v >> 4;
            const float* av = (j < 8) ? att_src1 : att_dst1;
            int h = j & 7;
            float s = 0.f;
            for (int c = 0; c < 32; ++c)
                s += W1[(size_t)k * 256 + 32 * h + c] * av[h * 32 + c];
            w1t[(size_t)(256 + j) * 128 + k] = f2bf(s);
        }
    }
}

// ---------- MFMA frag read: two ds_read_b64 (k-halves), XOR-swizzled rows ----------
__device__ __forceinline__ bf16x8 read_frag(const char* base, int row, int kb) {
    int swz = (row & 7) << 4;
    const char* p = base + row * 256;
    s16x4 lo = *(const s16x4*)(p + (kb ^ swz));
    s16x4 hi = *(const s16x4*)(p + ((kb + 32) ^ swz));
    return __builtin_shufflevector(lo, hi, 0, 1, 2, 3, 4, 5, 6, 7);
}

__device__ __forceinline__ void load_px(const float* __restrict__ x, int m0, int n, int t,
                                        f32x4 (&px)[2][4]) {
#pragma unroll
    for (int q = 0; q < 2; ++q) {
        int u = t + 256 * q;
        int row = u >> 3, kseg = u & 7;
        int gr = m0 + row;
        bool ok = (u < 384) && (gr < n);
        const f32x4* p = (const f32x4*)(x + (size_t)gr * 128 + kseg * 16);
#pragma unroll
        for (int j = 0; j < 4; ++j) {
            f32x4 z = {0.f, 0.f, 0.f, 0.f};
            px[q][j] = ok ? p[j] : z;
        }
    }
}

// ---------- layer-1 MFMA GEMM: h1[N,256] (+ fused a_src/a_dst via P columns) ----------
// block: 48 rows x 272 cols, K=128. LDS: W1T 272*256B (swz) + xtile 48*256B (swz) = 80KB.
#define XOFF 69632
__global__ __launch_bounds__(256, 2) void gemm1_kernel(
        const float* __restrict__ x, const unsigned short* __restrict__ w1t,
        unsigned short* __restrict__ h1u, float* __restrict__ asrc1,
        float* __restrict__ adst1, int n, int nchunk) {
    __shared__ __align__(16) char lds[81920];
    const int t = threadIdx.x;
    const int lane = t & 63, w = t >> 6;
    const int l15 = lane & 15, g = lane >> 4;

    // stage W1T -> LDS (swizzled)
    for (int u = t; u < 4352; u += 256) {
        int col = u >> 4, seg = u & 15;
        int4 v = *(const int4*)(w1t + (size_t)col * 128 + seg * 8);
        *(int4*)(lds + col * 256 + ((seg * 16) ^ ((col & 7) << 4))) = v;
    }

    int c0 = blockIdx.x * 2;
    f32x4 px[2][4];
    load_px(x, c0 * 48, n, t, px);
    __syncthreads();

    // hoist B fragments (wave w: cols 64w..64w+63; wave 0 also the 16 P-cols)
    bf16x8 Bf[4][5];
#pragma unroll
    for (int ks = 0; ks < 4; ++ks) {
#pragma unroll
        for (int nt = 0; nt < 5; ++nt) {
            if (nt < 4 || w == 0) {
                int col = (nt < 4) ? (64 * w + 16 * nt + l15) : (256 + l15);
                Bf[ks][nt] = read_frag(lds, col, 64 * ks + 8 * g);
            }
        }
    }

    for (int cc = 0; cc < 2; ++cc) {
        int chunk = c0 + cc;
        if (chunk >= nchunk) break;
        int m0 = chunk * 48;
        // write x tile (bf16, swizzled)
#pragma unroll
        for (int q = 0; q < 2; ++q) {
            int u = t + 256 * q;
            if (u < 384) {
                int row = u >> 3, kseg = u & 7;
                union { unsigned short us[16]; int4 v[2]; } pk;
#pragma unroll
                for (int j = 0; j < 4; ++j)
#pragma unroll
                    for (int e = 0; e < 4; ++e) pk.us[j * 4 + e] = f2bf(px[q][j][e]);
                int base = XOFF + row * 256;
                int swz = (row & 7) << 4;
                *(int4*)(lds + base + ((kseg * 32) ^ swz)) = pk.v[0];
                *(int4*)(lds + base + ((kseg * 32 + 16) ^ swz)) = pk.v[1];
            }
        }
        __syncthreads();
        if (cc == 0) load_px(x, (c0 + 1) * 48, n, t, px);

        f32x4 acc[3][5];
#pragma unroll
        for (int mt = 0; mt < 3; ++mt)
#pragma unroll
            for (int nt = 0; nt < 5; ++nt)
#pragma unroll
                for (int r = 0; r < 4; ++r) acc[mt][nt][r] = 0.f;

#pragma unroll
        for (int ks = 0; ks < 4; ++ks) {
            bf16x8 Af[3];
#pragma unroll
            for (int mt = 0; mt < 3; ++mt)
                Af[mt] = read_frag(lds + XOFF, mt * 16 + l15, 64 * ks + 8 * g);
#pragma unroll
            for (int nt = 0; nt < 5; ++nt) {
                if (nt < 4 || w == 0) {
#pragma unroll
                    for (int mt = 0; mt < 3; ++mt)
                        acc[mt][nt] = __builtin_amdgcn_mfma_f32_16x16x32_bf16(
                            Af[mt], Bf[ks][nt], acc[mt][nt], 0, 0, 0);
                }
            }
        }

        // epilogue: D layout col=lane&15, row=(lane>>4)*4+reg  [m89-verified]
#pragma unroll
        for (int mt = 0; mt < 3; ++mt) {
#pragma unroll
            for (int r = 0; r < 4; ++r) {
                int row = m0 + 16 * mt + 4 * g + r;
                bool ok = row < n;
#pragma unroll
                for (int nt = 0; nt < 4; ++nt)
                    if (ok) h1u[(size_t)row * 256 + 64 * w + 16 * nt + l15] =
                        f2bf(acc[mt][nt][r]);
                if (w == 0 && ok) {
                    float v = acc[mt][4][r];
                    if (l15 < 8) asrc1[(size_t)row * 8 + l15] = v;
                    else         adst1[(size_t)row * 8 + (l15 - 8)] = v;
                }
            }
        }
        if (cc == 0) __syncthreads();
    }
}

// ---------- stats: single pass, unnormalized exp -> alpha (bf16), per-head denom ----------
__global__ __launch_bounds__(64) void stats_kernel(
        const int* __restrict__ offs, const int* __restrict__ csr,
        const float* __restrict__ asrc1, const float* __restrict__ adst1,
        unsigned short* __restrict__ alphab, float* __restrict__ dn1) {
    int d = blockIdx.x;
    int lane = threadIdx.x;
    int h = lane & 7;
    int eg = lane >> 3;
    int off = offs[d], end = offs[d + 1];
    float ad = adst1[(size_t)d * 8 + h];
    float acc = 0.f;
    for (int i = off + eg; i < end; i += 8) {
        int s = csr[i];
        float a = asrc1[(size_t)s * 8 + h];
        float w = __expf(lrelu(a + ad));   // no-max: logits O(1), safe in fp32
        alphab[(size_t)i * 8 + h] = f2bf(w);
        acc += w;
    }
    acc += __shfl_xor(acc, 8);
    acc += __shfl_xor(acc, 16);
    acc += __shfl_xor(acc, 32);
    if (lane < 8) dn1[(size_t)d * 8 + lane] = acc;
}

// ---------- fused aggregate: 1 wave/node, 4 channels/lane ----------
__global__ __launch_bounds__(64) void aggregate_kernel(
        const int* __restrict__ offs, const int* __restrict__ csr,
        const unsigned short* __restrict__ alphab, const unsigned short* __restrict__ h1u,
        const float* __restrict__ dn1, const float* __restrict__ b1,
        const float* __restrict__ W2, const float* __restrict__ att_src2,
        const float* __restrict__ att_dst2, float4* __restrict__ rec) {
    int d = blockIdx.x;
    int t = threadIdx.x;          // lane: channels 4t..4t+3
    int h = t >> 3;               // head of these channels
    int off = offs[d], end = offs[d + 1];
    float a0 = 0.f, a1 = 0.f, a2 = 0.f, a3 = 0.f;
    int i = off;
    for (; i + 4 <= end; i += 4) {
        int s0 = csr[i], s1 = csr[i + 1], s2 = csr[i + 2], s3 = csr[i + 3];
        float al0 = bf2f(alphab[(size_t)(i + 0) * 8 + h]);
        float al1 = bf2f(alphab[(size_t)(i + 1) * 8 + h]);
        float al2 = bf2f(alphab[(size_t)(i + 2) * 8 + h]);
        float al3 = bf2f(alphab[(size_t)(i + 3) * 8 + h]);
        ushort4 v0 = *(const ushort4*)(h1u + (size_t)s0 * 256 + 4 * t);
        ushort4 v1 = *(const ushort4*)(h1u + (size_t)s1 * 256 + 4 * t);
        ushort4 v2 = *(const ushort4*)(h1u + (size_t)s2 * 256 + 4 * t);
        ushort4 v3 = *(const ushort4*)(h1u + (size_t)s3 * 256 + 4 * t);
        a0 = fmaf(al0, bf2f(v0.x), a0); a1 = fmaf(al0, bf2f(v0.y), a1);
        a2 = fmaf(al0, bf2f(v0.z), a2); a3 = fmaf(al0, bf2f(v0.w), a3);
        a0 = fmaf(al1, bf2f(v1.x), a0); a1 = fmaf(al1, bf2f(v1.y), a1);
        a2 = fmaf(al1, bf2f(v1.z), a2); a3 = fmaf(al1, bf2f(v1.w), a3);
        a0 = fmaf(al2, bf2f(v2.x), a0); a1 = fmaf(al2, bf2f(v2.y), a1);
        a2 = fmaf(al2, bf2f(v2.z), a2); a3 = fmaf(al2, bf2f(v2.w), a3);
        a0 = fmaf(al3, bf2f(v3.x), a0); a1 = fmaf(al3, bf2f(v3.y), a1);
        a2 = fmaf(al3, bf2f(v3.z), a2); a3 = fmaf(al3, bf2f(v3.w), a3);
    }
    for (; i < end; ++i) {
        int s = csr[i];
        float al = bf2f(alphab[(size_t)i * 8 + h]);
        ushort4 v = *(const ushort4*)(h1u + (size_t)s * 256 + 4 * t);
        a0 = fmaf(al, bf2f(v.x), a0); a1 = fmaf(al, bf2f(v.y), a1);
        a2 = fmaf(al, bf2f(v.z), a2); a3 = fmaf(al, bf2f(v.w), a3);
    }
    float inv = 1.0f / dn1[(size_t)d * 8 + h];
    float4 bv = *(const float4*)(b1 + 4 * t);
    float v0 = fmaf(a0, inv, bv.x);
    float v1 = fmaf(a1, inv, bv.y);
    float v2 = fmaf(a2, inv, bv.z);
    float v3 = fmaf(a3, inv, bv.w);
    v0 = v0 > 0.f ? v0 : __expf(v0) - 1.f;
    v1 = v1 > 0.f ? v1 : __expf(v1) - 1.f;
    v2 = v2 > 0.f ? v2 : __expf(v2) - 1.f;
    v3 = v3 > 0.f ? v3 : __expf(v3) - 1.f;
    float4 w01 = *(const float4*)(W2 + 8 * t);
    float4 w23 = *(const float4*)(W2 + 8 * t + 4);
    float p0 = v0 * w01.x + v1 * w01.z + v2 * w23.x + v3 * w23.z;
    float p1 = v0 * w01.y + v1 * w01.w + v2 * w23.y + v3 * w23.w;
#pragma unroll
    for (int o = 32; o; o >>= 1) { p0 += __shfl_down(p0, o); p1 += __shfl_down(p1, o); }
    if (t == 0) {
        float s2a = att_src2[0], s2b = att_src2[1];
        float d2a = att_dst2[0], d2b = att_dst2[1];
        rec[d] = make_float4(p0, p1, p0 * s2a + p1 * s2b, p0 * d2a + p1 * d2b);
    }
}

// ---------- layer-2: one float4 record gather per edge, no-max softmax ----------
__global__ __launch_bounds__(64) void layer2_kernel(
        const int* __restrict__ offs, const int* __restrict__ csr,
        const float4* __restrict__ rec, const float* __restrict__ b2,
        float* __restrict__ out) {
    int d = blockIdx.x;
    int lane = threadIdx.x;
    int off = offs[d], end = offs[d + 1];
    float ad = rec[d].w;
    float se = 0.f, s0 = 0.f, s1 = 0.f;
    for (int i = off + lane; i < end; i += 64) {
        int s = csr[i];
        float4 r = rec[s];
        float e = __expf(lrelu(r.z + ad));
        se += e;
        s0 = fmaf(e, r.x, s0);
        s1 = fmaf(e, r.y, s1);
    }
#pragma unroll
    for (int o = 32; o; o >>= 1) {
        se += __shfl_xor(se, o); s0 += __shfl_xor(s0, o); s1 += __shfl_xor(s1, o);
    }
    if (lane == 0) {
        float o0 = s0 / se + b2[0];
        float o1 = s1 / se + b2[1];
        float m2 = fmaxf(o0, o1);
        float lse = m2 + logf(__expf(o0 - m2) + __expf(o1 - m2));
        out[(size_t)d * 2 + 0] = o0 - lse;
        out[(size_t)d * 2 + 1] = o1 - lse;
    }
}

extern "C" void kernel_launch(void* const* d_in, const int* in_sizes, int n_in,
                              void* d_out, int out_size, void* d_ws, size_t ws_size,
                              hipStream_t stream) {
    const float* x        = (const float*)d_in[0];
    const int*   ei       = (const int*)d_in[1];
    const float* W1       = (const float*)d_in[2];
    const float* att_src1 = (const float*)d_in[3];
    const float* att_dst1 = (const float*)d_in[4];
    const float* b1       = (const float*)d_in[5];
    const float* W2       = (const float*)d_in[6];
    const float* att_src2 = (const float*)d_in[7];
    const float* att_dst2 = (const float*)d_in[8];
    const float* b2       = (const float*)d_in[9];
    float* out = (float*)d_out;

    int N = in_sizes[0] / 128;   // 50000
    int E = in_sizes[1] / 2;     // 800000
    int nb = (N + 255) / 256;
    int nchunk = (N + 47) / 48;

    // workspace layout (~49 MB)
    unsigned short* h1u = (unsigned short*)d_ws;                // N*256 bf16
    float* asrc1  = (float*)(h1u + (size_t)N * 256);            // N*8
    float* adst1  = asrc1 + (size_t)N * 8;                      // N*8
    unsigned short* alphab = (unsigned short*)(adst1 + (size_t)N * 8); // (E+N)*8 bf16
    float* dn1    = (float*)(alphab + (size_t)(E + N) * 8);     // N*8
    float4* rec   = (float4*)(dn1 + (size_t)N * 8);             // N
    unsigned short* w1t = (unsigned short*)(rec + N);           // 272*128 bf16
    int*   offs   = (int*)(w1t + 272 * 128);                    // N+1
    int*   cursor = offs + (N + 1);                             // N
    int*   bsum   = cursor + N;                                 // 4096
    int*   csr    = bsum + 4096;                                // E+N
    int*   flag   = csr + ((size_t)E + N);                      // 1

    init_kernel<<<nb, 256, 0, stream>>>(ei, flag, cursor, N);
    deg_kernel<<<(E + 255) / 256, 256, 0, stream>>>(ei, E, cursor, flag);
    scanA_kernel<<<nb, 256, 0, stream>>>(cursor, N, bsum);
    scanB_kernel<<<1, 256, 0, stream>>>(bsum, nb, offs, N);
    scanC_kernel<<<nb, 256, 0, stream>>>(cursor, N, bsum, offs);
    fill_kernel<<<(E + N + 255) / 256, 256, 0, stream>>>(ei, E, N, cursor, csr, flag);
    w1prep_kernel<<<129, 256, 0, stream>>>(W1, att_src1, att_dst1, w1t);
    gemm1_kernel<<<(nchunk + 1) / 2, 256, 0, stream>>>(x, w1t, h1u, asrc1, adst1, N, nchunk);
    stats_kernel<<<N, 64, 0, stream>>>(offs, csr, asrc1, adst1, alphab, dn1);
    aggregate_kernel<<<N, 64, 0, stream>>>(offs, csr, alphab, h1u, dn1, b1, W2,
                                           att_src2, att_dst2, rec);
    layer2_kernel<<<N, 64, 0, stream>>>(offs, csr, rec, b2, out);
}

// Round 5
// 257.463 us; speedup vs baseline: 2.0400x; 1.0003x over previous
//
#include <hip/hip_runtime.h>
#include <hip/hip_bf16.h>

#define NEG_SLOPE 0.2f

typedef float f32x4 __attribute__((ext_vector_type(4)));
typedef short s16x4 __attribute__((ext_vector_type(4)));
typedef short bf16x8 __attribute__((ext_vector_type(8)));

__device__ __forceinline__ float lrelu(float x) { return x > 0.f ? x : NEG_SLOPE * x; }
__device__ __forceinline__ float bf2f(unsigned short u) {
    return __uint_as_float(((unsigned int)u) << 16);
}
__device__ __forceinline__ unsigned short f2bf(float f) {   // RNE
    unsigned int u = __float_as_uint(f);
    return (unsigned short)((u + 0x7FFF + ((u >> 16) & 1)) >> 16);
}

// ---------- init: zero cursor + edge-index dtype detection ----------
__global__ void init_kernel(const int* __restrict__ ei, int* __restrict__ flag,
                            int* __restrict__ cursor, int n) {
    int i = blockIdx.x * 256 + threadIdx.x;
    if (i < n) cursor[i] = 0;
    if (i == 0) {
        int z = 1;
        for (int k = 0; k < 64; ++k) if (ei[2 * k + 1] != 0) { z = 0; break; }
        *flag = z;  // 1 => buffer is int64 little-endian
    }
}

__device__ __forceinline__ int load_src(const int* ei, int E, int e, int is64) {
    return is64 ? ei[2 * (size_t)e] : ei[e];
}
__device__ __forceinline__ int load_dst(const int* ei, int E, int e, int is64) {
    return is64 ? ei[2 * (size_t)E + 2 * (size_t)e] : ei[(size_t)E + e];
}

// ---------- CSR build ----------
__global__ void deg_kernel(const int* __restrict__ ei, int E, int* __restrict__ cnt,
                           const int* __restrict__ flag) {
    int e = blockIdx.x * blockDim.x + threadIdx.x;
    if (e < E) {
        int d = load_dst(ei, E, e, *flag);
        atomicAdd(&cnt[d], 1);
    }
}

__global__ void scanA_kernel(const int* __restrict__ cnt, int n, int* __restrict__ bsum) {
    int t = threadIdx.x;
    int i = blockIdx.x * 256 + t;
    int v = (i < n) ? cnt[i] + 1 : 0;
#pragma unroll
    for (int o = 32; o; o >>= 1) v += __shfl_down(v, o);
    __shared__ int ws[4];
    if ((t & 63) == 0) ws[t >> 6] = v;
    __syncthreads();
    if (t == 0) bsum[blockIdx.x] = ws[0] + ws[1] + ws[2] + ws[3];
}

__global__ void scanB_kernel(int* __restrict__ bsum, int nb, int* __restrict__ offs, int n) {
    __shared__ int sd[256];
    int t = threadIdx.x;
    int chunk = (nb + 255) / 256;
    int lo = t * chunk;
    int hi = lo + chunk; if (hi > nb) hi = nb;
    int s = 0;
    for (int i = lo; i < hi; ++i) s += bsum[i];
    sd[t] = s;
    __syncthreads();
    for (int o = 1; o < 256; o <<= 1) {
        int x = (t >= o) ? sd[t - o] : 0;
        __syncthreads();
        sd[t] += x;
        __syncthreads();
    }
    int run = sd[t] - s;
    for (int i = lo; i < hi; ++i) { int v = bsum[i]; bsum[i] = run; run += v; }
    if (t == 0) offs[n] = sd[255];
}

__global__ void scanC_kernel(int* __restrict__ cnt, int n, const int* __restrict__ bsum,
                             int* __restrict__ offs) {
    __shared__ int sd[256];
    int t = threadIdx.x;
    int i = blockIdx.x * 256 + t;
    int v = (i < n) ? cnt[i] + 1 : 0;
    sd[t] = v;
    __syncthreads();
    for (int o = 1; o < 256; o <<= 1) {
        int x = (t >= o) ? sd[t - o] : 0;
        __syncthreads();
        sd[t] += x;
        __syncthreads();
    }
    int excl = sd[t] - v + bsum[blockIdx.x];
    if (i < n) { offs[i] = excl; cnt[i] = excl; }
}

__global__ void fill_kernel(const int* __restrict__ ei, int E, int n,
                            int* __restrict__ cursor, int* __restrict__ csr,
                            const int* __restrict__ flag) {
    int e = blockIdx.x * blockDim.x + threadIdx.x;
    if (e < E + n) {
        int s, d;
        if (e < E) { int f = *flag; s = load_src(ei, E, e, f); d = load_dst(ei, E, e, f); }
        else       { s = d = e - E; }
        int pos = atomicAdd(&cursor[d], 1);
        csr[pos] = s;
    }
}

// ---------- prepass: W1T bf16 [272][128] = W1^T (256 rows) ++ P_src|P_dst (16 rows) ----------
// P[k][j] (j<8): sum_c W1[k][32j+c]*att_src1[j][c];  j in 8..15: att_dst1[j-8]
__global__ __launch_bounds__(256) void w1prep_kernel(
        const float* __restrict__ W1, const float* __restrict__ att_src1,
        const float* __restrict__ att_dst1, unsigned short* __restrict__ w1t) {
    int t = threadIdx.x;
    if (blockIdx.x < 128) {
        int v = blockIdx.x * 256 + t;       // 0..32767
        int col = v & 255, k = v >> 8;
        w1t[(size_t)col * 128 + k] = f2bf(W1[(size_t)k * 256 + col]);
    } else {
#pragma unroll
        for (int i = 0; i < 8; ++i) {
            int v = t + 256 * i;            // 0..2047
            int j = v & 15, k = v >> 4;
            const float* av = (j < 8) ? att_src1 : att_dst1;
            int h = j & 7;
            float s = 0.f;
            for (int c = 0; c < 32; ++c)
                s += W1[(size_t)k * 256 + 32 * h + c] * av[h * 32 + c];
            w1t[(size_t)(256 + j) * 128 + k] = f2bf(s);
        }
    }
}

// ---------- MFMA frag read: two ds_read_b64 (k-halves), XOR-swizzled rows ----------
__device__ __forceinline__ bf16x8 read_frag(const char* base, int row, int kb) {
    int swz = (row & 7) << 4;
    const char* p = base + row * 256;
    s16x4 lo = *(const s16x4*)(p + (kb ^ swz));
    s16x4 hi = *(const s16x4*)(p + ((kb + 32) ^ swz));
    return __builtin_shufflevector(lo, hi, 0, 1, 2, 3, 4, 5, 6, 7);
}

__device__ __forceinline__ void load_px(const float* __restrict__ x, int m0, int n, int t,
                                        f32x4 (&px)[2][4]) {
#pragma unroll
    for (int q = 0; q < 2; ++q) {
        int u = t + 256 * q;
        int row = u >> 3, kseg = u & 7;
        int gr = m0 + row;
        bool ok = (u < 384) && (gr < n);
        const f32x4* p = (const f32x4*)(x + (size_t)gr * 128 + kseg * 16);
#pragma unroll
        for (int j = 0; j < 4; ++j) {
            f32x4 z = {0.f, 0.f, 0.f, 0.f};
            px[q][j] = ok ? p[j] : z;
        }
    }
}

// ---------- layer-1 MFMA GEMM: h1[N,256] (+ fused a_src/a_dst via P columns) ----------
// block: 48 rows x 272 cols, K=128. LDS: W1T 272*256B (swz) + xtile 48*256B (swz) = 80KB.
#define XOFF 69632
__global__ __launch_bounds__(256, 2) void gemm1_kernel(
        const float* __restrict__ x, const unsigned short* __restrict__ w1t,
        unsigned short* __restrict__ h1u, float* __restrict__ asrc1,
        float* __restrict__ adst1, int n, int nchunk) {
    __shared__ __align__(16) char lds[81920];
    const int t = threadIdx.x;
    const int lane = t & 63, w = t >> 6;
    const int l15 = lane & 15, g = lane >> 4;

    // stage W1T -> LDS (swizzled)
    for (int u = t; u < 4352; u += 256) {
        int col = u >> 4, seg = u & 15;
        int4 v = *(const int4*)(w1t + (size_t)col * 128 + seg * 8);
        *(int4*)(lds + col * 256 + ((seg * 16) ^ ((col & 7) << 4))) = v;
    }

    int c0 = blockIdx.x * 2;
    f32x4 px[2][4];
    load_px(x, c0 * 48, n, t, px);
    __syncthreads();

    // hoist B fragments (wave w: cols 64w..64w+63; wave 0 also the 16 P-cols)
    bf16x8 Bf[4][5];
#pragma unroll
    for (int ks = 0; ks < 4; ++ks) {
#pragma unroll
        for (int nt = 0; nt < 5; ++nt) {
            if (nt < 4 || w == 0) {
                int col = (nt < 4) ? (64 * w + 16 * nt + l15) : (256 + l15);
                Bf[ks][nt] = read_frag(lds, col, 64 * ks + 8 * g);
            }
        }
    }

    for (int cc = 0; cc < 2; ++cc) {
        int chunk = c0 + cc;
        if (chunk >= nchunk) break;
        int m0 = chunk * 48;
        // write x tile (bf16, swizzled)
#pragma unroll
        for (int q = 0; q < 2; ++q) {
            int u = t + 256 * q;
            if (u < 384) {
                int row = u >> 3, kseg = u & 7;
                union { unsigned short us[16]; int4 v[2]; } pk;
#pragma unroll
                for (int j = 0; j < 4; ++j)
#pragma unroll
                    for (int e = 0; e < 4; ++e) pk.us[j * 4 + e] = f2bf(px[q][j][e]);
                int base = XOFF + row * 256;
                int swz = (row & 7) << 4;
                *(int4*)(lds + base + ((kseg * 32) ^ swz)) = pk.v[0];
                *(int4*)(lds + base + ((kseg * 32 + 16) ^ swz)) = pk.v[1];
            }
        }
        __syncthreads();
        if (cc == 0) load_px(x, (c0 + 1) * 48, n, t, px);

        f32x4 acc[3][5];
#pragma unroll
        for (int mt = 0; mt < 3; ++mt)
#pragma unroll
            for (int nt = 0; nt < 5; ++nt)
#pragma unroll
                for (int r = 0; r < 4; ++r) acc[mt][nt][r] = 0.f;

#pragma unroll
        for (int ks = 0; ks < 4; ++ks) {
            bf16x8 Af[3];
#pragma unroll
            for (int mt = 0; mt < 3; ++mt)
                Af[mt] = read_frag(lds + XOFF, mt * 16 + l15, 64 * ks + 8 * g);
#pragma unroll
            for (int nt = 0; nt < 5; ++nt) {
                if (nt < 4 || w == 0) {
#pragma unroll
                    for (int mt = 0; mt < 3; ++mt)
                        acc[mt][nt] = __builtin_amdgcn_mfma_f32_16x16x32_bf16(
                            Af[mt], Bf[ks][nt], acc[mt][nt], 0, 0, 0);
                }
            }
        }

        // epilogue: D layout col=lane&15, row=(lane>>4)*4+reg  [m89-verified]
#pragma unroll
        for (int mt = 0; mt < 3; ++mt) {
#pragma unroll
            for (int r = 0; r < 4; ++r) {
                int row = m0 + 16 * mt + 4 * g + r;
                bool ok = row < n;
#pragma unroll
                for (int nt = 0; nt < 4; ++nt)
                    if (ok) h1u[(size_t)row * 256 + 64 * w + 16 * nt + l15] =
                        f2bf(acc[mt][nt][r]);
                if (w == 0 && ok) {
                    float v = acc[mt][4][r];
                    if (l15 < 8) asrc1[(size_t)row * 8 + l15] = v;
                    else         adst1[(size_t)row * 8 + (l15 - 8)] = v;
                }
            }
        }
        if (cc == 0) __syncthreads();
    }
}

// ---------- stats: single pass, unnormalized exp -> alpha (bf16), per-head denom ----------
__global__ __launch_bounds__(64) void stats_kernel(
        const int* __restrict__ offs, const int* __restrict__ csr,
        const float* __restrict__ asrc1, const float* __restrict__ adst1,
        unsigned short* __restrict__ alphab, float* __restrict__ dn1) {
    int d = blockIdx.x;
    int lane = threadIdx.x;
    int h = lane & 7;
    int eg = lane >> 3;
    int off = offs[d], end = offs[d + 1];
    float ad = adst1[(size_t)d * 8 + h];
    float acc = 0.f;
    for (int i = off + eg; i < end; i += 8) {
        int s = csr[i];
        float a = asrc1[(size_t)s * 8 + h];
        float w = __expf(lrelu(a + ad));   // no-max: logits O(1), safe in fp32
        alphab[(size_t)i * 8 + h] = f2bf(w);
        acc += w;
    }
    acc += __shfl_xor(acc, 8);
    acc += __shfl_xor(acc, 16);
    acc += __shfl_xor(acc, 32);
    if (lane < 8) dn1[(size_t)d * 8 + lane] = acc;
}

// ---------- fused aggregate: 1 wave/node, 4 channels/lane ----------
__global__ __launch_bounds__(64) void aggregate_kernel(
        const int* __restrict__ offs, const int* __restrict__ csr,
        const unsigned short* __restrict__ alphab, const unsigned short* __restrict__ h1u,
        const float* __restrict__ dn1, const float* __restrict__ b1,
        const float* __restrict__ W2, const float* __restrict__ att_src2,
        const float* __restrict__ att_dst2, float4* __restrict__ rec) {
    int d = blockIdx.x;
    int t = threadIdx.x;          // lane: channels 4t..4t+3
    int h = t >> 3;               // head of these channels
    int off = offs[d], end = offs[d + 1];
    float a0 = 0.f, a1 = 0.f, a2 = 0.f, a3 = 0.f;
    int i = off;
    for (; i + 4 <= end; i += 4) {
        int s0 = csr[i], s1 = csr[i + 1], s2 = csr[i + 2], s3 = csr[i + 3];
        float al0 = bf2f(alphab[(size_t)(i + 0) * 8 + h]);
        float al1 = bf2f(alphab[(size_t)(i + 1) * 8 + h]);
        float al2 = bf2f(alphab[(size_t)(i + 2) * 8 + h]);
        float al3 = bf2f(alphab[(size_t)(i + 3) * 8 + h]);
        ushort4 v0 = *(const ushort4*)(h1u + (size_t)s0 * 256 + 4 * t);
        ushort4 v1 = *(const ushort4*)(h1u + (size_t)s1 * 256 + 4 * t);
        ushort4 v2 = *(const ushort4*)(h1u + (size_t)s2 * 256 + 4 * t);
        ushort4 v3 = *(const ushort4*)(h1u + (size_t)s3 * 256 + 4 * t);
        a0 = fmaf(al0, bf2f(v0.x), a0); a1 = fmaf(al0, bf2f(v0.y), a1);
        a2 = fmaf(al0, bf2f(v0.z), a2); a3 = fmaf(al0, bf2f(v0.w), a3);
        a0 = fmaf(al1, bf2f(v1.x), a0); a1 = fmaf(al1, bf2f(v1.y), a1);
        a2 = fmaf(al1, bf2f(v1.z), a2); a3 = fmaf(al1, bf2f(v1.w), a3);
        a0 = fmaf(al2, bf2f(v2.x), a0); a1 = fmaf(al2, bf2f(v2.y), a1);
        a2 = fmaf(al2, bf2f(v2.z), a2); a3 = fmaf(al2, bf2f(v2.w), a3);
        a0 = fmaf(al3, bf2f(v3.x), a0); a1 = fmaf(al3, bf2f(v3.y), a1);
        a2 = fmaf(al3, bf2f(v3.z), a2); a3 = fmaf(al3, bf2f(v3.w), a3);
    }
    for (; i < end; ++i) {
        int s = csr[i];
        float al = bf2f(alphab[(size_t)i * 8 + h]);
        ushort4 v = *(const ushort4*)(h1u + (size_t)s * 256 + 4 * t);
        a0 = fmaf(al, bf2f(v.x), a0); a1 = fmaf(al, bf2f(v.y), a1);
        a2 = fmaf(al, bf2f(v.z), a2); a3 = fmaf(al, bf2f(v.w), a3);
    }
    float inv = 1.0f / dn1[(size_t)d * 8 + h];
    float4 bv = *(const float4*)(b1 + 4 * t);
    float v0 = fmaf(a0, inv, bv.x);
    float v1 = fmaf(a1, inv, bv.y);
    float v2 = fmaf(a2, inv, bv.z);
    float v3 = fmaf(a3, inv, bv.w);
    v0 = v0 > 0.f ? v0 : __expf(v0) - 1.f;
    v1 = v1 > 0.f ? v1 : __expf(v1) - 1.f;
    v2 = v2 > 0.f ? v2 : __expf(v2) - 1.f;
    v3 = v3 > 0.f ? v3 : __expf(v3) - 1.f;
    float4 w01 = *(const float4*)(W2 + 8 * t);
    float4 w23 = *(const float4*)(W2 + 8 * t + 4);
    float p0 = v0 * w01.x + v1 * w01.z + v2 * w23.x + v3 * w23.z;
    float p1 = v0 * w01.y + v1 * w01.w + v2 * w23.y + v3 * w23.w;
#pragma unroll
    for (int o = 32; o; o >>= 1) { p0 += __shfl_down(p0, o); p1 += __shfl_down(p1, o); }
    if (t == 0) {
        float s2a = att_src2[0], s2b = att_src2[1];
        float d2a = att_dst2[0], d2b = att_dst2[1];
        rec[d] = make_float4(p0, p1, p0 * s2a + p1 * s2b, p0 * d2a + p1 * d2b);
    }
}

// ---------- layer-2: one float4 record gather per edge, no-max softmax ----------
__global__ __launch_bounds__(64) void layer2_kernel(
        const int* __restrict__ offs, const int* __restrict__ csr,
        const float4* __restrict__ rec, const float* __restrict__ b2,
        float* __restrict__ out) {
    int d = blockIdx.x;
    int lane = threadIdx.x;
    int off = offs[d], end = offs[d + 1];
    float ad = rec[d].w;
    float se = 0.f, s0 = 0.f, s1 = 0.f;
    for (int i = off + lane; i < end; i += 64) {
        int s = csr[i];
        float4 r = rec[s];
        float e = __expf(lrelu(r.z + ad));
        se += e;
        s0 = fmaf(e, r.x, s0);
        s1 = fmaf(e, r.y, s1);
    }
#pragma unroll
    for (int o = 32; o; o >>= 1) {
        se += __shfl_xor(se, o); s0 += __shfl_xor(s0, o); s1 += __shfl_xor(s1, o);
    }
    if (lane == 0) {
        float o0 = s0 / se + b2[0];
        float o1 = s1 / se + b2[1];
        float m2 = fmaxf(o0, o1);
        float lse = m2 + logf(__expf(o0 - m2) + __expf(o1 - m2));
        out[(size_t)d * 2 + 0] = o0 - lse;
        out[(size_t)d * 2 + 1] = o1 - lse;
    }
}

extern "C" void kernel_launch(void* const* d_in, const int* in_sizes, int n_in,
                              void* d_out, int out_size, void* d_ws, size_t ws_size,
                              hipStream_t stream) {
    const float* x        = (const float*)d_in[0];
    const int*   ei       = (const int*)d_in[1];
    const float* W1       = (const float*)d_in[2];
    const float* att_src1 = (const float*)d_in[3];
    const float* att_dst1 = (const float*)d_in[4];
    const float* b1       = (const float*)d_in[5];
    const float* W2       = (const float*)d_in[6];
    const float* att_src2 = (const float*)d_in[7];
    const float* att_dst2 = (const float*)d_in[8];
    const float* b2       = (const float*)d_in[9];
    float* out = (float*)d_out;

    int N = in_sizes[0] / 128;   // 50000
    int E = in_sizes[1] / 2;     // 800000
    int nb = (N + 255) / 256;
    int nchunk = (N + 47) / 48;

    // workspace layout (~49 MB)
    unsigned short* h1u = (unsigned short*)d_ws;                // N*256 bf16
    float* asrc1  = (float*)(h1u + (size_t)N * 256);            // N*8
    float* adst1  = asrc1 + (size_t)N * 8;                      // N*8
    unsigned short* alphab = (unsigned short*)(adst1 + (size_t)N * 8); // (E+N)*8 bf16
    float* dn1    = (float*)(alphab + (size_t)(E + N) * 8);     // N*8
    float4* rec   = (float4*)(dn1 + (size_t)N * 8);             // N
    unsigned short* w1t = (unsigned short*)(rec + N);           // 272*128 bf16
    int*   offs   = (int*)(w1t + 272 * 128);                    // N+1
    int*   cursor = offs + (N + 1);                             // N
    int*   bsum   = cursor + N;                                 // 4096
    int*   csr    = bsum + 4096;                                // E+N
    int*   flag   = csr + ((size_t)E + N);                      // 1

    init_kernel<<<nb, 256, 0, stream>>>(ei, flag, cursor, N);
    deg_kernel<<<(E + 255) / 256, 256, 0, stream>>>(ei, E, cursor, flag);
    scanA_kernel<<<nb, 256, 0, stream>>>(cursor, N, bsum);
    scanB_kernel<<<1, 256, 0, stream>>>(bsum, nb, offs, N);
    scanC_kernel<<<nb, 256, 0, stream>>>(cursor, N, bsum, offs);
    fill_kernel<<<(E + N + 255) / 256, 256, 0, stream>>>(ei, E, N, cursor, csr, flag);
    w1prep_kernel<<<129, 256, 0, stream>>>(W1, att_src1, att_dst1, w1t);
    gemm1_kernel<<<(nchunk + 1) / 2, 256, 0, stream>>>(x, w1t, h1u, asrc1, adst1, N, nchunk);
    stats_kernel<<<N, 64, 0, stream>>>(offs, csr, asrc1, adst1, alphab, dn1);
    aggregate_kernel<<<N, 64, 0, stream>>>(offs, csr, alphab, h1u, dn1, b1, W2,
                                           att_src2, att_dst2, rec);
    layer2_kernel<<<N, 64, 0, stream>>>(offs, csr, rec, b2, out);
}